// Round 5
// baseline (123.853 us; speedup 1.0000x reference)
//
#include <hip/hip_runtime.h>

#define BS 16
#define SEQL 2048
#define NH 16
#define PD 64
#define ND 16
#define LB 64
#define NC 32          // SEQL / LB
#define NHP (NH * PD)  // 1024
#define NHN (NH * ND)  // 256
#define PH 32          // p-columns per block (half of PD)

typedef __attribute__((ext_vector_type(8))) short bf16x8;
typedef __attribute__((ext_vector_type(4))) float f32x4;

static __device__ __forceinline__ unsigned short f2bf(float x) {
  unsigned int u = __float_as_uint(x);
  return (unsigned short)((u + 0x7FFFu + ((u >> 16) & 1u)) >> 16);  // RNE
}
static __device__ __forceinline__ unsigned int pk2(float a, float b) {
  return (unsigned int)f2bf(a) | ((unsigned int)f2bf(b) << 16);
}

// Grid 512 = 256 (b,h) x 2 p-halves; 256 threads = 4 waves. Two independent
// blocks per CU so one block's barrier/HBM stalls hide under the other's
// compute. Each block: sequential 32 chunks, ST[32p][16n] carried in LDS
// (fp32 + bf16 mirror, ping-pong). M computed redundantly per half.
__global__ __launch_bounds__(256) void ssd_fused(
    const float* __restrict__ Xg, const float* __restrict__ Ag,
    const float* __restrict__ Bg, const float* __restrict__ Cg,
    float* __restrict__ Yg) {
  const int bh = blockIdx.x & 255;   // sibling halves share XCD residue (mod 8)
  const int ph = blockIdx.x >> 8;
  const int h = bh & (NH - 1);
  const int b = bh >> 4;
  const int pc0 = h * PD + ph * PH;  // column base within an X/Y row
  const int t = threadIdx.x;
  const int w = t >> 6;
  const int lane = t & 63;
  const int g = lane >> 4;
  const int cc = lane & 15;

  // sXt row = 64 ushort = 128B = exactly 32 banks; 16B chunks XOR-swizzled by p
  __shared__ __align__(16) unsigned short sXt[PH][64];          // X^T[p][l]
  __shared__ __align__(16) unsigned short sM[LB][LB + 8];       // M[l][s]
  __shared__ __align__(16) unsigned short sB[LB][ND + 8];
  __shared__ __align__(16) unsigned short sC[LB][ND + 8];       // C' = e_l * C
  __shared__ __align__(16) unsigned short sBdT[ND][LB + 8];     // (dec*B)^T
  __shared__ __align__(16) float sSTf[2][PH][ND + 4];           // ST fp32 ping-pong
  __shared__ __align__(16) unsigned short sSTb[2][PH][ND + 8];  // ST bf16 mirror

  // thread maps
  const int xl0 = (t >> 3) * 2, xp0 = (t & 7) * 4;  // X: 2 l-rows x 4 p
  const int bcr = t >> 2, bcq = (t & 3) * 4;        // B/C: row, 4 n
  const int btn = t >> 4, btl = (t & 15) * 4;       // BdT: 1 n x 4 l

  float4 px0, px1, pb4, pc4;
  float pa, pt0, pt1, pt2, pt3;
  float er, rr, etot;

#define PREF(ci) do { \
    const size_t s0_ = (size_t)(b * SEQL + (ci) * LB); \
    px0 = *(const float4*)&Xg[(s0_ + xl0) * NHP + pc0 + xp0]; \
    px1 = *(const float4*)&Xg[(s0_ + xl0 + 1) * NHP + pc0 + xp0]; \
    pb4 = *(const float4*)&Bg[(s0_ + bcr) * NHN + h * ND + bcq]; \
    pc4 = *(const float4*)&Cg[(s0_ + bcr) * NHN + h * ND + bcq]; \
    pt0 = Bg[(s0_ + btl) * NHN + h * ND + btn]; \
    pt1 = Bg[(s0_ + btl + 1) * NHN + h * ND + btn]; \
    pt2 = Bg[(s0_ + btl + 2) * NHN + h * ND + btn]; \
    pt3 = Bg[(s0_ + btl + 3) * NHN + h * ND + btn]; \
    pa = Ag[(s0_ + lane) * NH + h]; \
  } while (0)

  const bf16x8 zf8 = {0, 0, 0, 0, 0, 0, 0, 0};

  auto xfrag = [&](int p_, int l0_) -> bf16x8 {
    return *(const bf16x8*)&sXt[p_][((l0_ >> 3) ^ (p_ & 7)) << 3];
  };

  auto p1tile = [&](int lb_, int sb_) {
    const int l_ = lb_ * 16 + cc;
    bf16x8 cf = zf8, bfr = zf8;
    if (g < 2) {
      cf = *(const bf16x8*)&sC[l_][g * 8];
      bfr = *(const bf16x8*)&sB[sb_ * 16 + cc][g * 8];
    }
    f32x4 z4 = {0.f, 0.f, 0.f, 0.f};
    f32x4 d = __builtin_amdgcn_mfma_f32_16x16x32_bf16(bfr, cf, z4, 0, 0, 0);
    // lane holds D'[s = sb*16+4g+r][l_]
    float mm[4];
#pragma unroll
    for (int r = 0; r < 4; ++r) {
      mm[r] = d[r] * __shfl(rr, sb_ * 16 + 4 * g + r);
      if (sb_ == lb_ && (4 * g + r) > cc) mm[r] = 0.f;
    }
    uint2 o;
    o.x = pk2(mm[0], mm[1]);
    o.y = pk2(mm[2], mm[3]);
    *(uint2*)&sM[l_][sb_ * 16 + g * 4] = o;
  };

  // ---------------- prologue ----------------
  for (int i = t; i < PH * (ND + 4); i += 256) ((float*)sSTf[0])[i] = 0.f;
  for (int i = t; i < PH * (ND + 8); i += 256) ((unsigned short*)sSTb[0])[i] = 0;
  PREF(0);

  for (int c = 0; c < NC; ++c) {
    const int cur = c & 1, nxt = cur ^ 1;

    // ---- stage (consumes prefetched regs) ----
    {
      float v = pa;
#pragma unroll
      for (int d = 1; d < 64; d <<= 1) {
        float o = __shfl_up(v, d, 64);
        if (lane >= d) v += o;
      }
      er = expf(v);
      rr = expf(-v);
      etot = __shfl(er, 63);
#pragma unroll
      for (int j = 0; j < 4; ++j) {
        const int p_ = xp0 + j;
        const int idx = (((xl0 >> 3) ^ (p_ & 7)) << 3) | (xl0 & 7);
        *(unsigned int*)&sXt[p_][idx] = pk2((&px0.x)[j], (&px1.x)[j]);
      }
      {
        const float el_ = __shfl(er, bcr);
        uint2 ub, uc;
        ub.x = pk2(pb4.x, pb4.y);
        ub.y = pk2(pb4.z, pb4.w);
        uc.x = pk2(el_ * pc4.x, el_ * pc4.y);
        uc.y = pk2(el_ * pc4.z, el_ * pc4.w);
        *(uint2*)&sB[bcr][bcq] = ub;
        *(uint2*)&sC[bcr][bcq] = uc;
      }
      {
        const float d0 = etot * __shfl(rr, btl);
        const float d1 = etot * __shfl(rr, btl + 1);
        const float d2 = etot * __shfl(rr, btl + 2);
        const float d3 = etot * __shfl(rr, btl + 3);
        uint2 ut;
        ut.x = pk2(d0 * pt0, d1 * pt1);
        ut.y = pk2(d2 * pt2, d3 * pt3);
        *(uint2*)&sBdT[btn][btl] = ut;
      }
    }
    if (c + 1 < NC) PREF(c + 1);
    __syncthreads();  // B1

    // ---- phase 1: 10 M-tiles (max 3/wave) + 2 zero tiles ----
    {
      const int lbA = (int)((0x0233u >> (4 * w)) & 0xFu);
      const int sbA = (int)((0x0020u >> (4 * w)) & 0xFu);
      const int lbB = (int)((0x1233u >> (4 * w)) & 0xFu);
      const int sbB = (int)((0x0131u >> (4 * w)) & 0xFu);
      p1tile(lbA, sbA);
      p1tile(lbB, sbB);
      if (w >= 2) {
        const int k = (w == 2) ? 2 : 1;
        p1tile(k, k);
      }
      if (w == 0) *(uint2*)&sM[cc][16 + g * 4] = make_uint2(0u, 0u);       // (0,1)
      if (w == 1) *(uint2*)&sM[32 + cc][48 + g * 4] = make_uint2(0u, 0u);  // (2,3)
    }
    __syncthreads();  // B2

    // ---- phase 2: Y (4 waves x 2 p-blocks) + S/ST (waves 0,1) ----
    {
      const int lY = w * 16 + cc;
      bf16x8 cfY = zf8;
      if (g < 2) cfY = *(const bf16x8*)&sC[lY][g * 8];
      bf16x8 a0 = *(const bf16x8*)&sM[lY][g * 8];
      bf16x8 a1 = zf8;
      if (w >= 2) a1 = *(const bf16x8*)&sM[lY][32 + g * 8];
#pragma unroll
      for (int pb = 0; pb < 2; ++pb) {
        const int p_ = pb * 16 + cc;
        bf16x8 stf = zf8;
        if (g < 2) stf = *(const bf16x8*)&sSTb[cur][p_][g * 8];
        f32x4 acc = {0.f, 0.f, 0.f, 0.f};
        acc = __builtin_amdgcn_mfma_f32_16x16x32_bf16(cfY, stf, acc, 0, 0, 0);
        acc = __builtin_amdgcn_mfma_f32_16x16x32_bf16(a0, xfrag(p_, g * 8), acc, 0, 0, 0);
        if (w >= 2)
          acc = __builtin_amdgcn_mfma_f32_16x16x32_bf16(a1, xfrag(p_, 32 + g * 8), acc, 0, 0, 0);
        const size_t yb =
            ((size_t)(b * SEQL + c * LB + w * 16 + 4 * g)) * NHP + pc0 + p_;
#pragma unroll
        for (int r = 0; r < 4; ++r) Yg[yb + (size_t)r * NHP] = acc[r];
      }
      if (w < 2) {
        const int pS = w * 16 + cc;
        bf16x8 ad0 = *(const bf16x8*)&sBdT[cc][g * 8];
        bf16x8 ad1 = *(const bf16x8*)&sBdT[cc][32 + g * 8];
        f32x4 s4 = {0.f, 0.f, 0.f, 0.f};
        s4 = __builtin_amdgcn_mfma_f32_16x16x32_bf16(ad0, xfrag(pS, g * 8), s4, 0, 0, 0);
        s4 = __builtin_amdgcn_mfma_f32_16x16x32_bf16(ad1, xfrag(pS, 32 + g * 8), s4, 0, 0, 0);
        // lane holds S[n = 4g+r][pS]
        float4 old = *(const float4*)&sSTf[cur][pS][4 * g];
        float4 nw;
        nw.x = old.x * etot + s4[0];
        nw.y = old.y * etot + s4[1];
        nw.z = old.z * etot + s4[2];
        nw.w = old.w * etot + s4[3];
        *(float4*)&sSTf[nxt][pS][4 * g] = nw;
        uint2 ub;
        ub.x = pk2(nw.x, nw.y);
        ub.y = pk2(nw.z, nw.w);
        *(uint2*)&sSTb[nxt][pS][4 * g] = ub;
      }
    }
    __syncthreads();  // B3 (protect sXt/sB/sC/sBdT before next stage)
  }
#undef PREF
}

extern "C" void kernel_launch(void* const* d_in, const int* in_sizes, int n_in,
                              void* d_out, int out_size, void* d_ws, size_t ws_size,
                              hipStream_t stream) {
  (void)in_sizes; (void)n_in; (void)out_size; (void)d_ws; (void)ws_size;
  const float* X = (const float*)d_in[0];
  const float* A = (const float*)d_in[1];
  const float* B = (const float*)d_in[2];
  const float* C = (const float*)d_in[3];
  float* Y = (float*)d_out;
  ssd_fused<<<2 * BS * NH, 256, 0, stream>>>(X, A, B, C, Y);
}

// Round 6
// 107.069 us; speedup vs baseline: 1.1568x; 1.1568x over previous
//
#include <hip/hip_runtime.h>

#define BS 16
#define SEQL 2048
#define NH 16
#define PD 64
#define ND 16
#define LB 64
#define NC 32          // SEQL / LB
#define NHP (NH * PD)  // 1024
#define NHN (NH * ND)  // 256

typedef __attribute__((ext_vector_type(8))) short bf16x8;
typedef __attribute__((ext_vector_type(4))) float f32x4;

static __device__ __forceinline__ unsigned short f2bf(float x) {
  unsigned int u = __float_as_uint(x);
  return (unsigned short)((u + 0x7FFFu + ((u >> 16) & 1u)) >> 16);  // RNE
}
static __device__ __forceinline__ unsigned int pk2(float a, float b) {
  return (unsigned int)f2bf(a) | ((unsigned int)f2bf(b) << 16);
}

// One block per (b,h), 8 waves, sequential over 32 chunks. ST carried in LDS
// (fp32 + bf16 mirror, ping-pong). Per chunk, 2 barriers:
//   [B1] phase1: M = tril(r_s * C'B^T) -> sM          (reads buf db)
//   [B2] phase2: Y = C'@ST^T + M@X  (waves 0-3)
//        phaseS: ST' = ST*etot + (dec B)^T@X (waves 4-7)
//        + PREF(c+1) issued at window start, stage(c+1)->buf nb at window end
//        (no barrier between issue and use -> no vmcnt(0) drain of prefetch)
__global__ __launch_bounds__(512) void ssd_fused(
    const float* __restrict__ Xg, const float* __restrict__ Ag,
    const float* __restrict__ Bg, const float* __restrict__ Cg,
    float* __restrict__ Yg) {
  const int h = blockIdx.x & (NH - 1);
  const int b = blockIdx.x >> 4;
  const int t = threadIdx.x;
  const int w = t >> 6;
  const int lane = t & 63;
  const int g = lane >> 4;
  const int cc = lane & 15;

  // sXt row = 128B; 16B chunks XOR-swizzled by p so transposed writes are 2-way
  __shared__ __align__(16) unsigned short sXt[2][PD][64];       // X^T[p][l]
  __shared__ __align__(16) unsigned short sM[LB][LB + 8];       // M[l][s]
  __shared__ __align__(16) unsigned short sB[2][LB][ND + 8];
  __shared__ __align__(16) unsigned short sC[2][LB][ND + 8];    // C' = e_l * C
  __shared__ __align__(16) unsigned short sBdT[2][ND][LB + 8];  // (dec*B)^T
  __shared__ __align__(16) float sSTf[2][PD][ND + 4];           // ST fp32 ping-pong
  __shared__ __align__(16) unsigned short sSTb[2][PD][ND + 8];  // ST bf16 mirror

  // thread maps
  const int xl0 = (t >> 4) * 2, xp0 = (t & 15) * 4;  // X: 2 l-rows x 4 p
  const int bl = t >> 3, bn0 = (t & 7) * 2;          // B/C: row, 2 n
  const int n_bt = t >> 5, l_bt = (t & 31) * 2;      // BdT: 1 n x 2 l

  float4 px0, px1;
  float2 pb2, pc2;
  float pbA_v, pbB_v, pa;
  float er, rr, etot;

#define PREF(ci) do { \
    const size_t s0_ = (size_t)(b * SEQL + (ci) * LB); \
    px0 = *(const float4*)&Xg[(s0_ + xl0) * NHP + h * PD + xp0]; \
    px1 = *(const float4*)&Xg[(s0_ + xl0 + 1) * NHP + h * PD + xp0]; \
    pb2 = *(const float2*)&Bg[(s0_ + bl) * NHN + h * ND + bn0]; \
    pc2 = *(const float2*)&Cg[(s0_ + bl) * NHN + h * ND + bn0]; \
    pbA_v = Bg[(s0_ + l_bt) * NHN + h * ND + n_bt]; \
    pbB_v = Bg[(s0_ + l_bt + 1) * NHN + h * ND + n_bt]; \
    pa = Ag[(s0_ + lane) * NH + h]; \
  } while (0)

#define CUMSUM_STAGE(bufi) do { \
    float v_ = pa; \
    _Pragma("unroll") \
    for (int d_ = 1; d_ < 64; d_ <<= 1) { \
      float o_ = __shfl_up(v_, d_, 64); \
      if (lane >= d_) v_ += o_; \
    } \
    er = expf(v_); rr = expf(-v_); etot = __shfl(er, 63); \
    _Pragma("unroll") \
    for (int j_ = 0; j_ < 4; ++j_) { \
      const int p_ = xp0 + j_; \
      const int idx_ = (((xl0 >> 3) ^ ((p_ >> 3) & 7)) << 3) | (xl0 & 7); \
      *(unsigned int*)&sXt[bufi][p_][idx_] = pk2((&px0.x)[j_], (&px1.x)[j_]); \
    } \
    { const float el_ = __shfl(er, bl); \
      *(unsigned int*)&sB[bufi][bl][bn0] = pk2(pb2.x, pb2.y); \
      *(unsigned int*)&sC[bufi][bl][bn0] = pk2(el_ * pc2.x, el_ * pc2.y); } \
    { const float d0_ = etot * __shfl(rr, l_bt); \
      const float d1_ = etot * __shfl(rr, l_bt + 1); \
      *(unsigned int*)&sBdT[bufi][n_bt][l_bt] = pk2(d0_ * pbA_v, d1_ * pbB_v); } \
  } while (0)

  const bf16x8 zf8 = {0, 0, 0, 0, 0, 0, 0, 0};

  auto xfrag = [&](int buf, int p_, int l0_) -> bf16x8 {
    return *(const bf16x8*)&sXt[buf][p_][(((l0_ >> 3) ^ ((p_ >> 3) & 7)) << 3)];
  };

  // ---------------- prologue ----------------
  for (int i = t; i < PD * (ND + 4); i += 512) ((float*)sSTf[0])[i] = 0.f;
  for (int i = t; i < PD * (ND + 8); i += 512) ((unsigned short*)sSTb[0])[i] = 0;
  PREF(0);
  CUMSUM_STAGE(0);

  for (int c = 0; c < NC; ++c) {
    const int db = c & 1, nb = db ^ 1;

    __syncthreads();  // B1: stage(c) visible

    // ---- phase 1: M tiles. wave w -> l-block w&3, s-blocks {0,1} or {2,3}
    {
      const int lb1 = w & 3;
      const int l = lb1 * 16 + cc;
      bf16x8 cf = zf8;
      if (g < 2) cf = *(const bf16x8*)&sC[db][l][g * 8];
#pragma unroll
      for (int ii = 0; ii < 2; ++ii) {
        const int sb = (w < 4 ? 0 : 2) + ii;
        uint2 out = make_uint2(0u, 0u);
        if (sb <= lb1) {
          bf16x8 bfr = zf8;
          if (g < 2) bfr = *(const bf16x8*)&sB[db][sb * 16 + cc][g * 8];
          f32x4 z4 = {0.f, 0.f, 0.f, 0.f};
          f32x4 d = __builtin_amdgcn_mfma_f32_16x16x32_bf16(bfr, cf, z4, 0, 0, 0);
          // lane holds D'[s = sb*16+4g+r][l]
          float m[4];
#pragma unroll
          for (int r = 0; r < 4; ++r) {
            m[r] = d[r] * __shfl(rr, sb * 16 + 4 * g + r);
            if (sb == lb1 && (4 * g + r) > cc) m[r] = 0.f;
          }
          out.x = pk2(m[0], m[1]);
          out.y = pk2(m[2], m[3]);
        }
        *(uint2*)&sM[l][sb * 16 + g * 4] = out;
      }
    }

    __syncthreads();  // B2: sM visible

    if (c + 1 < NC) PREF(c + 1);  // in flight across phase-2 window, no barrier
                                  // before consumption in CUMSUM_STAGE below

    if (w < 4) {
      // ---- phase 2: Y tiles. wave = l-block, loop p-blocks ----
      const int lb = w;
      const int l = lb * 16 + cc;
      bf16x8 cf = zf8;
      if (g < 2) cf = *(const bf16x8*)&sC[db][l][g * 8];
      bf16x8 a0 = *(const bf16x8*)&sM[l][g * 8];
      bf16x8 a1 = zf8;
      if (lb >= 2) a1 = *(const bf16x8*)&sM[l][32 + g * 8];
#pragma unroll
      for (int pb = 0; pb < 4; ++pb) {
        const int p = pb * 16 + cc;
        bf16x8 stf = zf8;
        if (g < 2) stf = *(const bf16x8*)&sSTb[db][p][g * 8];
        f32x4 acc = {0.f, 0.f, 0.f, 0.f};
        acc = __builtin_amdgcn_mfma_f32_16x16x32_bf16(cf, stf, acc, 0, 0, 0);
        acc = __builtin_amdgcn_mfma_f32_16x16x32_bf16(a0, xfrag(db, p, g * 8), acc, 0, 0, 0);
        if (lb >= 2)
          acc = __builtin_amdgcn_mfma_f32_16x16x32_bf16(a1, xfrag(db, p, 32 + g * 8), acc, 0, 0, 0);
        const size_t yb =
            ((size_t)(b * SEQL + c * LB + lb * 16 + 4 * g)) * NHP + h * PD + p;
#pragma unroll
        for (int r = 0; r < 4; ++r) Yg[yb + (size_t)r * NHP] = acc[r];
      }
    } else {
      // ---- phase S: ST' = ST*etot + (dec*B)^T @ X (ping-pong) ----
      const int pS = (w - 4) * 16 + cc;
      bf16x8 ad0 = *(const bf16x8*)&sBdT[db][cc][g * 8];
      bf16x8 ad1 = *(const bf16x8*)&sBdT[db][cc][32 + g * 8];
      f32x4 s4 = {0.f, 0.f, 0.f, 0.f};
      s4 = __builtin_amdgcn_mfma_f32_16x16x32_bf16(ad0, xfrag(db, pS, g * 8), s4, 0, 0, 0);
      s4 = __builtin_amdgcn_mfma_f32_16x16x32_bf16(ad1, xfrag(db, pS, 32 + g * 8), s4, 0, 0, 0);
      // lane holds S[n = 4g+r][pS]
      float4 old = *(const float4*)&sSTf[db][pS][4 * g];
      float4 nw;
      nw.x = old.x * etot + s4[0];
      nw.y = old.y * etot + s4[1];
      nw.z = old.z * etot + s4[2];
      nw.w = old.w * etot + s4[3];
      *(float4*)&sSTf[nb][pS][4 * g] = nw;
      uint2 ub;
      ub.x = pk2(nw.x, nw.y);
      ub.y = pk2(nw.z, nw.w);
      *(uint2*)&sSTb[nb][pS][4 * g] = ub;
    }

    // stage chunk c+1 into buffer nb (consumes prefetch regs; overlaps other
    // waves' phase-2 reads of buffer db — disjoint arrays, no barrier needed)
    if (c + 1 < NC) CUMSUM_STAGE(nb);
  }
#undef PREF
#undef CUMSUM_STAGE
}

extern "C" void kernel_launch(void* const* d_in, const int* in_sizes, int n_in,
                              void* d_out, int out_size, void* d_ws, size_t ws_size,
                              hipStream_t stream) {
  (void)in_sizes; (void)n_in; (void)out_size; (void)d_ws; (void)ws_size;
  const float* X = (const float*)d_in[0];
  const float* A = (const float*)d_in[1];
  const float* B = (const float*)d_in[2];
  const float* C = (const float*)d_in[3];
  float* Y = (float*)d_out;
  ssd_fused<<<BS * NH, 512, 0, stream>>>(X, A, B, C, Y);
}

// Round 7
// 80.149 us; speedup vs baseline: 1.5453x; 1.3359x over previous
//
#include <hip/hip_runtime.h>

#define BS 16
#define SEQL 2048
#define NH 16
#define PD 64
#define ND 16
#define LB 64
#define NC 32          // SEQL / LB
#define NHP (NH * PD)  // 1024
#define NHN (NH * ND)  // 256

typedef __attribute__((ext_vector_type(8))) short bf16x8;
typedef __attribute__((ext_vector_type(4))) float f32x4;

static __device__ __forceinline__ unsigned short f2bf(float x) {
  unsigned int u = __float_as_uint(x);
  return (unsigned short)((u + 0x7FFFu + ((u >> 16) & 1u)) >> 16);  // RNE
}
static __device__ __forceinline__ unsigned int pk2(float a, float b) {
  return (unsigned int)f2bf(a) | ((unsigned int)f2bf(b) << 16);
}

// LDS-only barrier: drains lgkmcnt (LDS) but NOT vmcnt, so global prefetch
// loads stay in flight across it (__syncthreads would drain vmcnt(0) and eat
// a full HBM latency per chunk). All cross-wave data here flows through LDS.
// sched_barrier(0) on both sides pins compiler scheduling (rule #18).
static __device__ __forceinline__ void barrier_lds() {
  __builtin_amdgcn_sched_barrier(0);
  asm volatile("s_waitcnt lgkmcnt(0)" ::: "memory");
  __builtin_amdgcn_s_barrier();
  __builtin_amdgcn_sched_barrier(0);
}

// One block per (b,h). 512 threads = 8 waves. Sequential over 32 chunks,
// carrying inter-chunk state ST[64p][16n] in LDS (fp32 recurrence + bf16
// mirror, ping-pong). Per chunk:
//   M[l][s]   = tril( r_s * sum_n C'[l,n] B[s,n] ),  C' = e_l * C
//   Y[l][p]   = sum_n C'[l,n] ST[p,n] + sum_s M[l,s] X[s,p]
//   ST'[p][n] = ST[p][n]*e_tot + sum_l dec_l B[l,n] X[l,p]
__global__ __launch_bounds__(512, 2) void ssd_fused(
    const float* __restrict__ Xg, const float* __restrict__ Ag,
    const float* __restrict__ Bg, const float* __restrict__ Cg,
    float* __restrict__ Yg) {
  const int h = blockIdx.x & (NH - 1);
  const int b = blockIdx.x >> 4;
  const int t = threadIdx.x;
  const int w = t >> 6;
  const int lane = t & 63;
  const int g = lane >> 4;     // k-group 0..3
  const int cc = lane & 15;

  __shared__ __align__(16) unsigned short sXt[PD][LB + 8];   // X^T[p][l] bf16
  __shared__ __align__(16) unsigned short sM [LB][LB + 8];   // M[l][s] bf16
  __shared__ __align__(16) unsigned short sB [LB][ND + 8];   // B[l][n] bf16
  __shared__ __align__(16) unsigned short sC [LB][ND + 8];   // C'[l][n] bf16
  __shared__ __align__(16) unsigned short sBdT[ND][LB + 8];  // (dec*B)^T[n][l] bf16
  __shared__ __align__(16) float          sSTf[2][PD][ND + 4]; // ST fp32 ping-pong
  __shared__ __align__(16) unsigned short sSTb[2][PD][ND + 8]; // ST bf16 mirror

  // zero initial state (read at c=0)
  for (int i = t; i < PD * (ND + 4); i += 512) ((float*)sSTf[0])[i] = 0.f;
  for (int i = t; i < PD * (ND + 8); i += 512) ((unsigned short*)sSTb[0])[i] = 0;

  // prefetch register staging
  const int xl0 = (t >> 4) * 2, xp0 = (t & 15) * 4;   // X: 2 rows x float4
  const int bl  = t >> 3,       bn0 = (t & 7) * 2;    // B/C: 1 row x float2
  float4 px0, px1; float2 pb2, pc2; float pa;

#define PREF(cc_) do { \
    const size_t s0_ = (size_t)(b * SEQL + (cc_) * LB); \
    px0 = *(const float4*)&Xg[(s0_ + xl0) * NHP + h * PD + xp0]; \
    px1 = *(const float4*)&Xg[(s0_ + xl0 + 1) * NHP + h * PD + xp0]; \
    pb2 = *(const float2*)&Bg[(s0_ + bl) * NHN + h * ND + bn0]; \
    pc2 = *(const float2*)&Cg[(s0_ + bl) * NHN + h * ND + bn0]; \
    pa  = Ag[(s0_ + lane) * NH + h]; \
  } while (0)

  PREF(0);

  for (int c = 0; c < NC; ++c) {
    // ---- per-wave redundant cumsum of A (all 8 waves) ----
    float v = pa;
#pragma unroll
    for (int d = 1; d < 64; d <<= 1) {
      float o = __shfl_up(v, d, 64);
      if (lane >= d) v += o;
    }
    const float acs = v;
    const float er = expf(acs);          // e_l (lane l)   <= 1
    const float rr = expf(-acs);         // r_s (lane s)
    const float etot = __shfl(er, 63);   // exp(A_total)

    // ---- staging writes (bf16) ----
    {
#pragma unroll
      for (int j = 0; j < 4; ++j) {
        const float xa = (&px0.x)[j], xb = (&px1.x)[j];
        *(unsigned int*)&sXt[xp0 + j][xl0] = pk2(xa, xb);
      }
      const float el = __shfl(er, bl);
      const float dl = etot * __shfl(rr, bl);   // dec_l = exp(Atot - acs_l)
      *(unsigned int*)&sB[bl][bn0] = pk2(pb2.x, pb2.y);
      *(unsigned int*)&sC[bl][bn0] = pk2(el * pc2.x, el * pc2.y);
      sBdT[bn0][bl]     = f2bf(dl * pb2.x);
      sBdT[bn0 + 1][bl] = f2bf(dl * pb2.y);
    }
    if (c + 1 < NC) PREF(c + 1);   // stays in flight across ALL lgkm barriers;
                                   // consumed at top of next chunk
    barrier_lds();  // B1

    // ---- phase 1: M tiles. wave w -> l-block w&3, s-blocks {0,1} or {2,3}
    {
      const int lb1 = w & 3;
      const int l = lb1 * 16 + cc;
      bf16x8 zf = {0, 0, 0, 0, 0, 0, 0, 0};
      bf16x8 cf = zf;
      if (g < 2) cf = *(const bf16x8*)&sC[l][g * 8];
#pragma unroll
      for (int ii = 0; ii < 2; ++ii) {
        const int sb = (w < 4 ? 0 : 2) + ii;
        uint2 out = make_uint2(0u, 0u);
        if (sb <= lb1) {
          bf16x8 bfr = zf;
          if (g < 2) bfr = *(const bf16x8*)&sB[sb * 16 + cc][g * 8];
          f32x4 z4 = {0.f, 0.f, 0.f, 0.f};
          f32x4 d = __builtin_amdgcn_mfma_f32_16x16x32_bf16(bfr, cf, z4, 0, 0, 0);
          // lane holds D'[s = sb*16+4g+r][l]
          float m[4];
#pragma unroll
          for (int r = 0; r < 4; ++r) {
            const int srow = sb * 16 + 4 * g + r;
            m[r] = d[r] * __shfl(rr, srow);
            if (sb == lb1 && (4 * g + r) > cc) m[r] = 0.f;
          }
          out.x = pk2(m[0], m[1]);
          out.y = pk2(m[2], m[3]);
        }
        *(uint2*)&sM[l][sb * 16 + g * 4] = out;
      }
    }
    barrier_lds();  // B2

    const int cur = c & 1, nxt = cur ^ 1;
    if (w < 4) {
      // ---- phase 2: Y tiles. wave = l-block, loop p-blocks ----
      const int lb = w;
      const int l = lb * 16 + cc;
      bf16x8 zf = {0, 0, 0, 0, 0, 0, 0, 0};
      bf16x8 cf = zf;
      if (g < 2) cf = *(const bf16x8*)&sC[l][g * 8];
      bf16x8 a0 = *(const bf16x8*)&sM[l][g * 8];
      bf16x8 a1 = zf;
      if (lb >= 2) a1 = *(const bf16x8*)&sM[l][32 + g * 8];
#pragma unroll
      for (int pb = 0; pb < 4; ++pb) {
        const int p = pb * 16 + cc;
        bf16x8 stf = zf;
        if (g < 2) stf = *(const bf16x8*)&sSTb[cur][p][g * 8];
        f32x4 acc = {0.f, 0.f, 0.f, 0.f};
        acc = __builtin_amdgcn_mfma_f32_16x16x32_bf16(cf, stf, acc, 0, 0, 0);
        bf16x8 xf0 = *(const bf16x8*)&sXt[p][g * 8];
        acc = __builtin_amdgcn_mfma_f32_16x16x32_bf16(a0, xf0, acc, 0, 0, 0);
        if (lb >= 2) {
          bf16x8 xf1 = *(const bf16x8*)&sXt[p][32 + g * 8];
          acc = __builtin_amdgcn_mfma_f32_16x16x32_bf16(a1, xf1, acc, 0, 0, 0);
        }
        const size_t yb =
            ((size_t)(b * SEQL + c * LB + lb * 16 + 4 * g)) * NHP + h * PD + p;
#pragma unroll
        for (int r = 0; r < 4; ++r)
          Yg[yb + (size_t)r * NHP] = acc[r];
      }
    } else {
      // ---- phase S: S[n][p] = (dec*B)^T @ X ; ST update (ping-pong) ----
      const int pb = w - 4;
      const int p = pb * 16 + cc;
      bf16x8 ad0 = *(const bf16x8*)&sBdT[cc][g * 8];
      bf16x8 ad1 = *(const bf16x8*)&sBdT[cc][32 + g * 8];
      bf16x8 xt0 = *(const bf16x8*)&sXt[p][g * 8];
      bf16x8 xt1 = *(const bf16x8*)&sXt[p][32 + g * 8];
      f32x4 acc = {0.f, 0.f, 0.f, 0.f};
      acc = __builtin_amdgcn_mfma_f32_16x16x32_bf16(ad0, xt0, acc, 0, 0, 0);
      acc = __builtin_amdgcn_mfma_f32_16x16x32_bf16(ad1, xt1, acc, 0, 0, 0);
      // lane holds S[n = 4g+r][p]
      float4 old = *(const float4*)&sSTf[cur][p][4 * g];
      float4 nw;
      nw.x = old.x * etot + acc[0];
      nw.y = old.y * etot + acc[1];
      nw.z = old.z * etot + acc[2];
      nw.w = old.w * etot + acc[3];
      *(float4*)&sSTf[nxt][p][4 * g] = nw;
      uint2 ub;
      ub.x = pk2(nw.x, nw.y);
      ub.y = pk2(nw.z, nw.w);
      *(uint2*)&sSTb[nxt][p][4 * g] = ub;
    }
    barrier_lds();  // B3
  }
#undef PREF
}

extern "C" void kernel_launch(void* const* d_in, const int* in_sizes, int n_in,
                              void* d_out, int out_size, void* d_ws, size_t ws_size,
                              hipStream_t stream) {
  (void)in_sizes; (void)n_in; (void)out_size; (void)d_ws; (void)ws_size;
  const float* X = (const float*)d_in[0];
  const float* A = (const float*)d_in[1];
  const float* B = (const float*)d_in[2];
  const float* C = (const float*)d_in[3];
  float* Y = (float*)d_out;
  ssd_fused<<<BS * NH, 512, 0, stream>>>(X, A, B, C, Y);
}

// Round 8
// 76.418 us; speedup vs baseline: 1.6207x; 1.0488x over previous
//
#include <hip/hip_runtime.h>

#define BS 16
#define SEQL 2048
#define NH 16
#define PD 64
#define ND 16
#define LB 64
#define NC 32          // SEQL / LB
#define NHP (NH * PD)  // 1024
#define NHN (NH * ND)  // 256

typedef __attribute__((ext_vector_type(8))) short bf16x8;
typedef __attribute__((ext_vector_type(4))) float f32x4;

static __device__ __forceinline__ unsigned short f2bf(float x) {
  unsigned int u = __float_as_uint(x);
  return (unsigned short)((u + 0x7FFFu + ((u >> 16) & 1u)) >> 16);  // RNE
}
static __device__ __forceinline__ unsigned int pk2(float a, float b) {
  return (unsigned int)f2bf(a) | ((unsigned int)f2bf(b) << 16);
}

// LDS-only barrier (drains lgkmcnt, NOT vmcnt): global prefetch loads stay in
// flight across it. All cross-wave data flows through LDS.
static __device__ __forceinline__ void barrier_lds() {
  __builtin_amdgcn_sched_barrier(0);
  asm volatile("s_waitcnt lgkmcnt(0)" ::: "memory");
  __builtin_amdgcn_s_barrier();
  __builtin_amdgcn_sched_barrier(0);
}

// k-slot permutation pi(g,u): slot m=8g+u (within a 32-wide pair) holds
//   l = 4g+u (u<4)  or  16+4g+(u-4) (u>=4);  pairs are l-blocks {0,1},{2,3}.
// This makes the p1tile MFMA output order (lane cc: l=cc, s=4g+r) directly
// usable as an A-fragment, so M never touches LDS. X^T and (dec*B)^T are
// staged with the SAME permutation (MFMA invariant to consistent k-permute).
static __device__ __forceinline__ int invperm(int l) {
  const int jp = l >> 5, v = l & 31;
  return jp * 32 + (v < 16 ? (((v >> 2) << 3) | (v & 3))
                           : ((((v - 16) >> 2) << 3) | 4 | ((v - 16) & 3)));
}

// One block per (b,h). 8 waves, sequential over 32 chunks, ST in LDS
// (fp32 recurrence + bf16 mirror, ping-pong). 2 barriers per chunk.
__global__ __launch_bounds__(512) void ssd_fused(
    const float* __restrict__ Xg, const float* __restrict__ Ag,
    const float* __restrict__ Bg, const float* __restrict__ Cg,
    float* __restrict__ Yg) {
  const int h = blockIdx.x & (NH - 1);
  const int b = blockIdx.x >> 4;
  const int t = threadIdx.x;
  const int w = t >> 6;
  const int lane = t & 63;
  const int g = lane >> 4;
  const int cc = lane & 15;

  // sXt row = 128B (32 banks); 16B chunks XOR-swizzled by (p>>3)
  __shared__ __align__(16) unsigned short sXt[PD][64];          // X^T permuted
  __shared__ __align__(16) unsigned short sB[LB][ND + 8];       // B[l][n]
  __shared__ __align__(16) unsigned short sC[LB][ND + 8];       // C' = e_l*C
  __shared__ __align__(16) unsigned short sBdT[ND][LB + 8];     // (dec*B)^T perm cols
  __shared__ __align__(16) float sSTf[2][PD][ND + 4];           // ST fp32 ping-pong
  __shared__ __align__(16) unsigned short sSTb[2][PD][ND + 8];  // ST bf16 mirror
  __shared__ float sER[NC][LB];   // exp(+acs)
  __shared__ float sRR[NC][LB];   // exp(-acs)
  __shared__ float sEtot[NC];

  // ---- prologue: decay tables for ALL chunks (off the per-chunk path) ----
  {
    float av[4];
#pragma unroll
    for (int k = 0; k < 4; ++k)
      av[k] = Ag[((size_t)(b * SEQL + (w + 8 * k) * LB + lane)) * NH + h];
#pragma unroll
    for (int k = 0; k < 4; ++k) {
      const int c = w + 8 * k;
      float v = av[k];
#pragma unroll
      for (int d = 1; d < 64; d <<= 1) {
        float o = __shfl_up(v, d, 64);
        if (lane >= d) v += o;
      }
      const float e = expf(v);
      sER[c][lane] = e;
      sRR[c][lane] = expf(-v);
      if (lane == 63) sEtot[c] = e;
    }
  }
  for (int i = t; i < PD * (ND + 4); i += 512) ((float*)sSTf[0])[i] = 0.f;
  for (int i = t; i < PD * (ND + 8); i += 512) ((unsigned short*)sSTb[0])[i] = 0;

  // thread maps
  const int xl0 = (t >> 4) * 2, xp0 = (t & 15) * 4;  // X: 2 l x 4 p
  const int bl = t >> 3, bn0 = (t & 7) * 2;          // B/C: 1 row x 2 n
  const int mX = invperm(xl0);                       // X col pair -> phys pair
  const int mB = invperm(bl);                        // BdT col
  float4 px0, px1;
  float2 pb2, pc2;

#define PREF(ci) do { \
    const size_t s0_ = (size_t)(b * SEQL + (ci) * LB); \
    px0 = *(const float4*)&Xg[(s0_ + xl0) * NHP + h * PD + xp0]; \
    px1 = *(const float4*)&Xg[(s0_ + xl0 + 1) * NHP + h * PD + xp0]; \
    pb2 = *(const float2*)&Bg[(s0_ + bl) * NHN + h * ND + bn0]; \
    pc2 = *(const float2*)&Cg[(s0_ + bl) * NHN + h * ND + bn0]; \
  } while (0)

  const bf16x8 zf8 = {0, 0, 0, 0, 0, 0, 0, 0};
  auto xfrag = [&](int p_, int kb) -> bf16x8 {  // kb = logical 16B chunk 0..7
    return *(const bf16x8*)&sXt[p_][(kb ^ ((p_ >> 3) & 7)) << 3];
  };

  PREF(0);
  __syncthreads();  // tables + ST init visible

  for (int c = 0; c < NC; ++c) {
    // ---- staging (no cumsum: tables are precomputed) ----
    {
#pragma unroll
      for (int j = 0; j < 4; ++j) {
        const int p_ = xp0 + j;
        const int mm = ((((mX >> 3) ^ ((p_ >> 3) & 7)) << 3) | (mX & 7));
        *(unsigned int*)&sXt[p_][mm] = pk2((&px0.x)[j], (&px1.x)[j]);
      }
      const float el = sER[c][bl];
      const float dl = sEtot[c] * sRR[c][bl];  // exp(Atot - acs_l)
      *(unsigned int*)&sB[bl][bn0] = pk2(pb2.x, pb2.y);
      *(unsigned int*)&sC[bl][bn0] = pk2(el * pc2.x, el * pc2.y);
      sBdT[bn0][mB] = f2bf(dl * pb2.x);
      sBdT[bn0 + 1][mB] = f2bf(dl * pb2.y);
    }
    if (c + 1 < NC) PREF(c + 1);  // in flight across both lgkm barriers
    barrier_lds();  // B1: staged data visible

    const int cur = c & 1, nxt = cur ^ 1;
    if (w < 4) {
      // ---- build own M-row A-fragments in registers, then Y tiles ----
      const int lb = w;
      const int l = lb * 16 + cc;
      bf16x8 cf = zf8;
      if (g < 2) cf = *(const bf16x8*)&sC[l][g * 8];
      auto mtile = [&](int sb, bool mask) -> uint2 {
        bf16x8 bfr = zf8;
        if (g < 2) bfr = *(const bf16x8*)&sB[sb * 16 + cc][g * 8];
        f32x4 z4 = {0.f, 0.f, 0.f, 0.f};
        f32x4 d = __builtin_amdgcn_mfma_f32_16x16x32_bf16(bfr, cf, z4, 0, 0, 0);
        // lane holds D'[s = sb*16+4g+r][l]
        float m[4];
#pragma unroll
        for (int r = 0; r < 4; ++r) {
          m[r] = d[r] * sRR[c][sb * 16 + 4 * g + r];
          if (mask && (4 * g + r) > cc) m[r] = 0.f;
        }
        return make_uint2(pk2(m[0], m[1]), pk2(m[2], m[3]));
      };
      union {
        bf16x8 v;
        unsigned int u[4];
      } mf0, mf1;
      mf0.u[0] = mf0.u[1] = mf0.u[2] = mf0.u[3] = 0u;
      mf1.u[0] = mf1.u[1] = mf1.u[2] = mf1.u[3] = 0u;
      if (lb == 0) {
        const uint2 t0 = mtile(0, true);
        mf0.u[0] = t0.x; mf0.u[1] = t0.y;
      } else if (lb == 1) {
        const uint2 t0 = mtile(0, false), t1 = mtile(1, true);
        mf0.u[0] = t0.x; mf0.u[1] = t0.y; mf0.u[2] = t1.x; mf0.u[3] = t1.y;
      } else if (lb == 2) {
        const uint2 t0 = mtile(0, false), t1 = mtile(1, false), t2 = mtile(2, true);
        mf0.u[0] = t0.x; mf0.u[1] = t0.y; mf0.u[2] = t1.x; mf0.u[3] = t1.y;
        mf1.u[0] = t2.x; mf1.u[1] = t2.y;
      } else {
        const uint2 t0 = mtile(0, false), t1 = mtile(1, false);
        const uint2 t2 = mtile(2, false), t3 = mtile(3, true);
        mf0.u[0] = t0.x; mf0.u[1] = t0.y; mf0.u[2] = t1.x; mf0.u[3] = t1.y;
        mf1.u[0] = t2.x; mf1.u[1] = t2.y; mf1.u[2] = t3.x; mf1.u[3] = t3.y;
      }
      // Y[l][p] = C'@ST^T + M@X   (k-order of mf matches permuted sXt)
#pragma unroll
      for (int pb = 0; pb < 4; ++pb) {
        const int p = pb * 16 + cc;
        bf16x8 stf = zf8;
        if (g < 2) stf = *(const bf16x8*)&sSTb[cur][p][g * 8];
        f32x4 acc = {0.f, 0.f, 0.f, 0.f};
        acc = __builtin_amdgcn_mfma_f32_16x16x32_bf16(cf, stf, acc, 0, 0, 0);
        acc = __builtin_amdgcn_mfma_f32_16x16x32_bf16(mf0.v, xfrag(p, g), acc, 0, 0, 0);
        if (lb >= 2)
          acc = __builtin_amdgcn_mfma_f32_16x16x32_bf16(mf1.v, xfrag(p, 4 + g), acc, 0, 0, 0);
        const size_t yb =
            ((size_t)(b * SEQL + c * LB + lb * 16 + 4 * g)) * NHP + h * PD + p;
#pragma unroll
        for (int r = 0; r < 4; ++r) Yg[yb + (size_t)r * NHP] = acc[r];
      }
    } else {
      // ---- phase S: ST' = ST*etot + (dec*B)^T @ X  (ping-pong) ----
      const int pS = (w - 4) * 16 + cc;
      bf16x8 ad0 = *(const bf16x8*)&sBdT[cc][g * 8];
      bf16x8 ad1 = *(const bf16x8*)&sBdT[cc][32 + g * 8];
      f32x4 s4 = {0.f, 0.f, 0.f, 0.f};
      s4 = __builtin_amdgcn_mfma_f32_16x16x32_bf16(ad0, xfrag(pS, g), s4, 0, 0, 0);
      s4 = __builtin_amdgcn_mfma_f32_16x16x32_bf16(ad1, xfrag(pS, 4 + g), s4, 0, 0, 0);
      const float etot = sEtot[c];
      // lane holds S[n = 4g+r][pS]
      float4 old = *(const float4*)&sSTf[cur][pS][4 * g];
      float4 nw;
      nw.x = old.x * etot + s4[0];
      nw.y = old.y * etot + s4[1];
      nw.z = old.z * etot + s4[2];
      nw.w = old.w * etot + s4[3];
      *(float4*)&sSTf[nxt][pS][4 * g] = nw;
      uint2 ub;
      ub.x = pk2(nw.x, nw.y);
      ub.y = pk2(nw.z, nw.w);
      *(uint2*)&sSTb[nxt][pS][4 * g] = ub;
    }
    barrier_lds();  // B2: end of chunk (staging may overwrite next iter)
  }
#undef PREF
}

extern "C" void kernel_launch(void* const* d_in, const int* in_sizes, int n_in,
                              void* d_out, int out_size, void* d_ws, size_t ws_size,
                              hipStream_t stream) {
  (void)in_sizes; (void)n_in; (void)out_size; (void)d_ws; (void)ws_size;
  const float* X = (const float*)d_in[0];
  const float* A = (const float*)d_in[1];
  const float* B = (const float*)d_in[2];
  const float* C = (const float*)d_in[3];
  float* Y = (float*)d_out;
  ssd_fused<<<BS * NH, 512, 0, stream>>>(X, A, B, C, Y);
}

// Round 9
// 75.565 us; speedup vs baseline: 1.6390x; 1.0113x over previous
//
#include <hip/hip_runtime.h>

#define BS 16
#define SEQL 2048
#define NH 16
#define PD 64
#define ND 16
#define LB 64
#define NC 32          // SEQL / LB
#define NHP (NH * PD)  // 1024
#define NHN (NH * ND)  // 256

typedef __attribute__((ext_vector_type(8))) short bf16x8;
typedef __attribute__((ext_vector_type(4))) float f32x4;

static __device__ __forceinline__ unsigned short f2bf(float x) {
  unsigned int u = __float_as_uint(x);
  return (unsigned short)((u + 0x7FFFu + ((u >> 16) & 1u)) >> 16);  // RNE
}
static __device__ __forceinline__ unsigned int pk2(float a, float b) {
  return (unsigned int)f2bf(a) | ((unsigned int)f2bf(b) << 16);
}

// LDS-only barrier (drains lgkmcnt, NOT vmcnt): global prefetch loads stay in
// flight across it. All cross-wave data flows through LDS.
static __device__ __forceinline__ void barrier_lds() {
  __builtin_amdgcn_sched_barrier(0);
  asm volatile("s_waitcnt lgkmcnt(0)" ::: "memory");
  __builtin_amdgcn_s_barrier();
  __builtin_amdgcn_sched_barrier(0);
}

// k-slot permutation pi: slot m=8g+u holds l = 4g+u (u<4) or 16+4g+(u-4)
// (u>=4) within each 32-l pair; makes the mtile MFMA output order directly
// usable as an A-fragment (M never touches LDS). X^T and (dec*B)^T staged
// with the SAME permutation (MFMA invariant to consistent k-permute).
static __device__ __forceinline__ int invperm(int l) {
  const int jp = l >> 5, v = l & 31;
  return jp * 32 + (v < 16 ? (((v >> 2) << 3) | (v & 3))
                           : ((((v - 16) >> 2) << 3) | 4 | ((v - 16) & 3)));
}

// One block per (b,h), 8 waves, 32 sequential chunks, ONE barrier per chunk.
// Wave pair (2k,2k+1) owns l-block k (redundant M-frag build); each wave does
// 2 p-blocks of Y; waves 0-3 also do one p-block of the S/ST update.
// Staging double-buffered so stage(c+1) overlaps compute(c) in one window.
__global__ __launch_bounds__(512) void ssd_fused(
    const float* __restrict__ Xg, const float* __restrict__ Ag,
    const float* __restrict__ Bg, const float* __restrict__ Cg,
    float* __restrict__ Yg) {
  const int h = blockIdx.x & (NH - 1);
  const int b = blockIdx.x >> 4;
  const int t = threadIdx.x;
  const int w = t >> 6;
  const int lane = t & 63;
  const int g = lane >> 4;
  const int cc = lane & 15;

  __shared__ __align__(16) unsigned short sXt[2][PD][64];       // X^T permuted
  __shared__ __align__(16) unsigned short sB[2][LB][ND + 8];
  __shared__ __align__(16) unsigned short sC[2][LB][ND + 8];    // C' = e_l*C
  __shared__ __align__(16) unsigned short sBdT[2][ND][LB + 8];  // (dec*B)^T perm
  __shared__ __align__(16) float sSTf[2][PD][ND + 4];           // ST fp32 ping-pong
  __shared__ __align__(16) unsigned short sSTb[2][PD][ND + 8];  // ST bf16 mirror
  __shared__ float sER[NC][LB];   // exp(+acs)
  __shared__ float sRR[NC][LB];   // exp(-acs)
  __shared__ float sEtot[NC];

  // ---- prologue: decay tables for ALL chunks ----
  {
    float av[4];
#pragma unroll
    for (int k = 0; k < 4; ++k)
      av[k] = Ag[((size_t)(b * SEQL + (w + 8 * k) * LB + lane)) * NH + h];
#pragma unroll
    for (int k = 0; k < 4; ++k) {
      const int c = w + 8 * k;
      float v = av[k];
#pragma unroll
      for (int d = 1; d < 64; d <<= 1) {
        float o = __shfl_up(v, d, 64);
        if (lane >= d) v += o;
      }
      const float e = expf(v);
      sER[c][lane] = e;
      sRR[c][lane] = expf(-v);
      if (lane == 63) sEtot[c] = e;
    }
  }
  for (int i = t; i < PD * (ND + 4); i += 512) ((float*)sSTf[0])[i] = 0.f;
  for (int i = t; i < PD * (ND + 8); i += 512) ((unsigned short*)sSTb[0])[i] = 0;

  // thread maps
  const int xl0 = (t >> 4) * 2, xp0 = (t & 15) * 4;  // X: 2 l x 4 p
  const int bl = t >> 3, bn0 = (t & 7) * 2;          // B/C: 1 row x 2 n
  const int mX = invperm(xl0);
  const int mB = invperm(bl);
  float4 px0, px1;
  float2 pb2, pc2;

#define PREF(ci) do { \
    const size_t s0_ = (size_t)(b * SEQL + (ci) * LB); \
    px0 = *(const float4*)&Xg[(s0_ + xl0) * NHP + h * PD + xp0]; \
    px1 = *(const float4*)&Xg[(s0_ + xl0 + 1) * NHP + h * PD + xp0]; \
    pb2 = *(const float2*)&Bg[(s0_ + bl) * NHN + h * ND + bn0]; \
    pc2 = *(const float2*)&Cg[(s0_ + bl) * NHN + h * ND + bn0]; \
  } while (0)

#define STAGE(bufi, ci) do { \
    _Pragma("unroll") \
    for (int j_ = 0; j_ < 4; ++j_) { \
      const int p_ = xp0 + j_; \
      const int mm_ = ((((mX >> 3) ^ ((p_ >> 3) & 7)) << 3) | (mX & 7)); \
      *(unsigned int*)&sXt[bufi][p_][mm_] = pk2((&px0.x)[j_], (&px1.x)[j_]); \
    } \
    { const float el_ = sER[ci][bl]; \
      const float dl_ = sEtot[ci] * sRR[ci][bl]; \
      *(unsigned int*)&sB[bufi][bl][bn0] = pk2(pb2.x, pb2.y); \
      *(unsigned int*)&sC[bufi][bl][bn0] = pk2(el_ * pc2.x, el_ * pc2.y); \
      sBdT[bufi][bn0][mB] = f2bf(dl_ * pb2.x); \
      sBdT[bufi][bn0 + 1][mB] = f2bf(dl_ * pb2.y); } \
  } while (0)

  const bf16x8 zf8 = {0, 0, 0, 0, 0, 0, 0, 0};
  auto xfrag = [&](int buf, int p_, int kb) -> bf16x8 {
    return *(const bf16x8*)&sXt[buf][p_][(kb ^ ((p_ >> 3) & 7)) << 3];
  };

  PREF(0);
  STAGE(0, 0);
  PREF(1);
  barrier_lds();  // tables + ST init + stage(0) visible

  const int lb = w >> 1;            // l-block owned by this wave's pair
  const int pb0 = (w & 1) * 2;      // first of two Y p-blocks
  const int l = lb * 16 + cc;

  for (int c = 0; c < NC; ++c) {
    const int db = c & 1, nb = db ^ 1;

    // ---- M-frags in registers (redundant within wave pair) ----
    bf16x8 cf = zf8;
    if (g < 2) cf = *(const bf16x8*)&sC[db][l][g * 8];
    auto mtile = [&](int sb, bool mask) -> uint2 {
      bf16x8 bfr = zf8;
      if (g < 2) bfr = *(const bf16x8*)&sB[db][sb * 16 + cc][g * 8];
      f32x4 z4 = {0.f, 0.f, 0.f, 0.f};
      f32x4 d = __builtin_amdgcn_mfma_f32_16x16x32_bf16(bfr, cf, z4, 0, 0, 0);
      // lane holds D'[s = sb*16+4g+r][l]
      float m[4];
#pragma unroll
      for (int r = 0; r < 4; ++r) {
        m[r] = d[r] * sRR[c][sb * 16 + 4 * g + r];
        if (mask && (4 * g + r) > cc) m[r] = 0.f;
      }
      return make_uint2(pk2(m[0], m[1]), pk2(m[2], m[3]));
    };
    union { bf16x8 v; unsigned int u[4]; } mf0, mf1;
    mf0.u[0] = mf0.u[1] = mf0.u[2] = mf0.u[3] = 0u;
    mf1.u[0] = mf1.u[1] = mf1.u[2] = mf1.u[3] = 0u;
    if (lb == 0) {
      const uint2 t0 = mtile(0, true);
      mf0.u[0] = t0.x; mf0.u[1] = t0.y;
    } else if (lb == 1) {
      const uint2 t0 = mtile(0, false), t1 = mtile(1, true);
      mf0.u[0] = t0.x; mf0.u[1] = t0.y; mf0.u[2] = t1.x; mf0.u[3] = t1.y;
    } else if (lb == 2) {
      const uint2 t0 = mtile(0, false), t1 = mtile(1, false), t2 = mtile(2, true);
      mf0.u[0] = t0.x; mf0.u[1] = t0.y; mf0.u[2] = t1.x; mf0.u[3] = t1.y;
      mf1.u[0] = t2.x; mf1.u[1] = t2.y;
    } else {
      const uint2 t0 = mtile(0, false), t1 = mtile(1, false);
      const uint2 t2 = mtile(2, false), t3 = mtile(3, true);
      mf0.u[0] = t0.x; mf0.u[1] = t0.y; mf0.u[2] = t1.x; mf0.u[3] = t1.y;
      mf1.u[0] = t2.x; mf1.u[1] = t2.y; mf1.u[2] = t3.x; mf1.u[3] = t3.y;
    }

    // ---- Y tiles: 2 p-blocks per wave ----
#pragma unroll
    for (int pbi = 0; pbi < 2; ++pbi) {
      const int p = (pb0 + pbi) * 16 + cc;
      bf16x8 stf = zf8;
      if (g < 2) stf = *(const bf16x8*)&sSTb[db][p][g * 8];
      f32x4 acc = {0.f, 0.f, 0.f, 0.f};
      acc = __builtin_amdgcn_mfma_f32_16x16x32_bf16(cf, stf, acc, 0, 0, 0);
      acc = __builtin_amdgcn_mfma_f32_16x16x32_bf16(mf0.v, xfrag(db, p, g), acc, 0, 0, 0);
      if (lb >= 2)
        acc = __builtin_amdgcn_mfma_f32_16x16x32_bf16(mf1.v, xfrag(db, p, 4 + g), acc, 0, 0, 0);
      const size_t yb =
          ((size_t)(b * SEQL + c * LB + lb * 16 + 4 * g)) * NHP + h * PD + p;
#pragma unroll
      for (int r = 0; r < 4; ++r) Yg[yb + (size_t)r * NHP] = acc[r];
    }

    // ---- S/ST update on the light waves (0-3), one p-block each ----
    if (w < 4) {
      const int pS = w * 16 + cc;
      bf16x8 ad0 = *(const bf16x8*)&sBdT[db][cc][g * 8];
      bf16x8 ad1 = *(const bf16x8*)&sBdT[db][cc][32 + g * 8];
      f32x4 s4 = {0.f, 0.f, 0.f, 0.f};
      s4 = __builtin_amdgcn_mfma_f32_16x16x32_bf16(ad0, xfrag(db, pS, g), s4, 0, 0, 0);
      s4 = __builtin_amdgcn_mfma_f32_16x16x32_bf16(ad1, xfrag(db, pS, 4 + g), s4, 0, 0, 0);
      const float etot = sEtot[c];
      // lane holds S[n = 4g+r][pS]
      float4 old = *(const float4*)&sSTf[db][pS][4 * g];
      float4 nw;
      nw.x = old.x * etot + s4[0];
      nw.y = old.y * etot + s4[1];
      nw.z = old.z * etot + s4[2];
      nw.w = old.w * etot + s4[3];
      *(float4*)&sSTf[nb][pS][4 * g] = nw;
      uint2 ub;
      ub.x = pk2(nw.x, nw.y);
      ub.y = pk2(nw.z, nw.w);
      *(uint2*)&sSTb[nb][pS][4 * g] = ub;
    }

    // ---- stage chunk c+1 into buf nb (overlaps compute above) ----
    if (c + 1 < NC) {
      STAGE(nb, c + 1);
      if (c + 2 < NC) PREF(c + 2);
    }
    barrier_lds();  // end of window: staged data + ST[nb] visible
  }
#undef PREF
#undef STAGE
}

extern "C" void kernel_launch(void* const* d_in, const int* in_sizes, int n_in,
                              void* d_out, int out_size, void* d_ws, size_t ws_size,
                              hipStream_t stream) {
  (void)in_sizes; (void)n_in; (void)out_size; (void)d_ws; (void)ws_size;
  const float* X = (const float*)d_in[0];
  const float* A = (const float*)d_in[1];
  const float* B = (const float*)d_in[2];
  const float* C = (const float*)d_in[3];
  float* Y = (float*)d_out;
  ssd_fused<<<BS * NH, 512, 0, stream>>>(X, A, B, C, Y);
}